// Round 1
// 145.660 us; speedup vs baseline: 1.0545x; 1.0545x over previous
//
#include <hip/hip_runtime.h>

// Problem constants (from reference): B=8, E=512, L=4096, D=256, all fp32.
#define B_N 8
#define E_N 512
#define L_N 4096
#define D_N 256

#define SPLITK 8
#define KC_LEN (L_N / SPLITK)   // 512
#define BK 64
#define KC_ITERS (KC_LEN / BK)  // 8

#define ET 128                  // E tile
#define DT 128                  // D tile
#define NTHREADS 512

// LDS leading dim (shorts): 64 data + 8 pad (keeps b128 frag reads 16B-aligned).
#define LDT 72

typedef __attribute__((ext_vector_type(8))) short short8;   // 8 bf16 (MFMA A/B frag)
typedef __attribute__((ext_vector_type(4))) short short4v;  // 4 bf16 = 8B LDS store
typedef __attribute__((ext_vector_type(4))) float f32x4;    // MFMA acc / global float4

// round-to-nearest-even fp32 -> bf16 bits
__device__ __forceinline__ unsigned short f2bf(float f) {
    unsigned u = __float_as_uint(f);
    u += 0x7fffu + ((u >> 16) & 1u);
    return (unsigned short)(u >> 16);
}

__global__ __launch_bounds__(NTHREADS, 4)   // cap VGPR at 128 -> 2 blocks/CU
void mp_gemm(const float* __restrict__ doc,   // [B, L, D]
             const float* __restrict__ map,   // [B, E, L]
             const float* __restrict__ lens,  // [B, E]
             float* __restrict__ out)         // [B, E, D] (pre-zeroed; atomic accumulate)
{
    __shared__ unsigned short As[ET * LDT];   // As[m][k] : map tile, K-contig
    __shared__ unsigned short Bs[DT * LDT];   // Bs[n][k] : doc tile transposed, K-contig
    __shared__ float invLen[ET];

    // XCD-chunked swizzle: assuming XCD(p) = p % 8, physical p -> logical w so each
    // XCD owns a contiguous 64-wide w-range = 8 complete (b,kc) groups. All 8 tiles
    // of a group (4 E-tiles sharing doc, 2 D-tiles sharing map) are co-resident on
    // one XCD's L2. Bijective: 512 % 8 == 0.
    const int p    = (int)blockIdx.x;            // 0..511
    const int w    = ((p & 7) << 6) | (p >> 3);
    const int tile = w & 7;        // et*2 + dt
    const int grp  = w >> 3;       // 0..63
    const int b    = grp & 7;
    const int kc   = grp >> 3;     // 0..7

    const int e0  = (tile >> 1) * ET;   // 4 E tiles
    const int d0  = (tile & 1) * DT;    // 2 D tiles
    const int kc0 = kc * KC_LEN;

    const float* docB = doc + (size_t)b * L_N * D_N;
    const float* mapB = map + (size_t)b * E_N * L_N;
    float*       outB = out + (size_t)b * E_N * D_N;

    const int tid  = threadIdx.x;
    const int lane = tid & 63;
    const int wave = tid >> 6;     // 0..7

    if (tid < ET) invLen[tid] = 1.0f / lens[(size_t)b * E_N + e0 + tid];

    // ---- staging assignments ----
    // A tile 128(m) x 64(k) fp32: thread t handles rows (t>>4)+32r, col4 = t&15
    //   -> per instruction: 16 lanes x 16B = 256B contiguous per row (full lines)
    const int aRow0 = tid >> 4;    // 0..31
    const int aCol4 = tid & 15;
    // B tile 64(k) x 128(n) fp32: each thread owns one 4x4 micro-block, transposes in regs
    //   -> per instruction: 32 lanes x 16B = 512B contiguous per k-row
    const int nb = tid & 31;       // n block
    const int kb = tid >> 5;       // k block (0..15)

    f32x4 ar[4], br[4];

    // prefetch tile 0
    {
        const int k0 = kc0;
        #pragma unroll
        for (int r = 0; r < 4; ++r)
            ar[r] = *(const f32x4*)(mapB + (size_t)(e0 + aRow0 + r * 32) * L_N + k0 + aCol4 * 4);
        #pragma unroll
        for (int i = 0; i < 4; ++i)
            br[i] = *(const f32x4*)(docB + (size_t)(k0 + kb * 4 + i) * D_N + d0 + nb * 4);
    }

    // ---- compute setup: 8 waves in 2(m) x 4(n) grid; each wave 64x32 output ----
    const int wm = wave >> 2;      // 0..1 : 64-row block
    const int wn = wave & 3;       // 0..3 : 32-col block
    const int fm = lane & 15;
    const int q  = lane >> 4;

    f32x4 acc[4][2] = {};

    for (int it = 0; it < KC_ITERS; ++it) {
        if (it) __syncthreads();            // all waves done reading previous tile

        // regs -> LDS (with fp32->bf16 convert; B transposed 4x4)
        #pragma unroll
        for (int r = 0; r < 4; ++r) {
            short4v wv;
            wv[0] = (short)f2bf(ar[r][0]);
            wv[1] = (short)f2bf(ar[r][1]);
            wv[2] = (short)f2bf(ar[r][2]);
            wv[3] = (short)f2bf(ar[r][3]);
            *(short4v*)&As[(aRow0 + r * 32) * LDT + aCol4 * 4] = wv;
        }
        #pragma unroll
        for (int j = 0; j < 4; ++j) {
            short4v wv;
            wv[0] = (short)f2bf(br[0][j]);
            wv[1] = (short)f2bf(br[1][j]);
            wv[2] = (short)f2bf(br[2][j]);
            wv[3] = (short)f2bf(br[3][j]);
            *(short4v*)&Bs[(nb * 4 + j) * LDT + kb * 4] = wv;
        }
        __syncthreads();

        // prefetch next tile into regs (overlaps with MFMA below)
        if (it < KC_ITERS - 1) {
            const int k0 = kc0 + (it + 1) * BK;
            #pragma unroll
            for (int r = 0; r < 4; ++r)
                ar[r] = *(const f32x4*)(mapB + (size_t)(e0 + aRow0 + r * 32) * L_N + k0 + aCol4 * 4);
            #pragma unroll
            for (int i = 0; i < 4; ++i)
                br[i] = *(const f32x4*)(docB + (size_t)(k0 + kb * 4 + i) * D_N + d0 + nb * 4);
        }

        // compute on the staged 128x128x64 tile: 2 K-steps of 32
        #pragma unroll
        for (int kk = 0; kk < 2; ++kk) {
            short8 af[4], bf[2];
            #pragma unroll
            for (int mi = 0; mi < 4; ++mi)
                af[mi] = *(const short8*)&As[(wm * 64 + mi * 16 + fm) * LDT + kk * 32 + q * 8];
            #pragma unroll
            for (int ni = 0; ni < 2; ++ni)
                bf[ni] = *(const short8*)&Bs[(wn * 32 + ni * 16 + fm) * LDT + kk * 32 + q * 8];
            #pragma unroll
            for (int mi = 0; mi < 4; ++mi)
                #pragma unroll
                for (int ni = 0; ni < 2; ++ni)
                    acc[mi][ni] = __builtin_amdgcn_mfma_f32_16x16x32_bf16(
                        af[mi], bf[ni], acc[mi][ni], 0, 0, 0);
        }
    }

    // ---- epilogue: scale partial by invLen (linear in split-K) and atomically accumulate.
    // C/D layout: col = lane&15, row = (lane>>4)*4 + i
    #pragma unroll
    for (int mi = 0; mi < 4; ++mi) {
        const int rLoc = wm * 64 + mi * 16 + q * 4;
        #pragma unroll
        for (int ni = 0; ni < 2; ++ni) {
            const int c = d0 + wn * 32 + ni * 16 + fm;
            #pragma unroll
            for (int i = 0; i < 4; ++i) {
                const int rr = rLoc + i;
                atomicAdd(&outB[(size_t)(e0 + rr) * D_N + c], acc[mi][ni][i] * invLen[rr]);
            }
        }
    }
}

extern "C" void kernel_launch(void* const* d_in, const int* in_sizes, int n_in,
                              void* d_out, int out_size, void* d_ws, size_t ws_size,
                              hipStream_t stream) {
    const float* doc  = (const float*)d_in[0];  // doc_state [B,L,D]
    const float* map  = (const float*)d_in[1];  // entity_mapping [B,E,L]
    const float* lens = (const float*)d_in[2];  // entity_lens [B,E]
    float* out = (float*)d_out;                 // [B,E,D] fp32

    // d_out is poisoned 0xAA before every call; split-K accumulates atomically.
    hipMemsetAsync(out, 0, (size_t)out_size * sizeof(float), stream);

    dim3 grid(SPLITK * 8 * B_N);   // 512 blocks: (E/128)*(D/128)=8 tiles x 8 b x 8 kc
    mp_gemm<<<grid, NTHREADS, 0, stream>>>(doc, map, lens, out);
}